// Round 3
// baseline (101.292 us; speedup 1.0000x reference)
//
#include <hip/hip_runtime.h>
#include <math.h>

#define F_IN 256
#define NTREES 512
#define DEPTH 6
#define NCOLS (NTREES * DEPTH)   /* 3072 */
#define BATCH 512
#define OUTW (NTREES * 3)        /* 1536 */

// ---------------------------------------------------------------------------
// Kernel 1: exact 1.5-entmax along axis 0 (F=256) for each of 3072 columns.
// Newton root-solve of f(tau) = sum max(z-tau,0)^2 - 1 (convex, decreasing).
// One wave per column, 4 elements/lane, 4 columns in flight per wave.
// Output written TRANSPOSED: cwT[n][f], so the fused kernel reads coalesced
// 256B row segments.
// ---------------------------------------------------------------------------
__global__ __launch_bounds__(256) void k_entmax(const float* __restrict__ att,
                                                float* __restrict__ cwT) {
    const int n0 = blockIdx.x * 16;
    const int tid = threadIdx.x;
    const int lane = tid & 63;
    const int w = tid >> 6;                 // wave id 0..3
    __shared__ float s_z[16][260];

    // coalesced load: 16 columns x 256 rows, transposed into LDS
    const int cld = tid & 15;
#pragma unroll
    for (int it = 0; it < 16; ++it) {
        int f = (tid >> 4) + it * 16;
        s_z[cld][f] = att[f * NCOLS + n0 + cld];
    }
    __syncthreads();

    float4 z[4];
    float m[4], tau[4];
#pragma unroll
    for (int c = 0; c < 4; ++c) {
        float4 v = *(const float4*)&s_z[w * 4 + c][4 * lane];
        z[c] = make_float4(v.x * 0.5f, v.y * 0.5f, v.z * 0.5f, v.w * 0.5f);
        m[c] = fmaxf(fmaxf(z[c].x, z[c].y), fmaxf(z[c].z, z[c].w));
    }
#pragma unroll
    for (int off = 32; off >= 1; off >>= 1)
#pragma unroll
        for (int c = 0; c < 4; ++c)
            m[c] = fmaxf(m[c], __shfl_xor(m[c], off));
#pragma unroll
    for (int c = 0; c < 4; ++c) {
        z[c].x -= m[c]; z[c].y -= m[c]; z[c].z -= m[c]; z[c].w -= m[c];
        tau[c] = -1.0f;                     // f(zmax-1) >= 0 guaranteed
    }

    for (int iter = 0; iter < 14; ++iter) {
        float S1[4], S2[4];
#pragma unroll
        for (int c = 0; c < 4; ++c) {
            float d0 = fmaxf(z[c].x - tau[c], 0.f);
            float d1 = fmaxf(z[c].y - tau[c], 0.f);
            float d2 = fmaxf(z[c].z - tau[c], 0.f);
            float d3 = fmaxf(z[c].w - tau[c], 0.f);
            S1[c] = (d0 + d1) + (d2 + d3);
            S2[c] = fmaf(d0, d0, fmaf(d1, d1, fmaf(d2, d2, d3 * d3)));
        }
#pragma unroll
        for (int off = 32; off >= 1; off >>= 1)
#pragma unroll
            for (int c = 0; c < 4; ++c) {
                S1[c] += __shfl_xor(S1[c], off);
                S2[c] += __shfl_xor(S2[c], off);
            }
        bool done = true;
#pragma unroll
        for (int c = 0; c < 4; ++c) {
            tau[c] += (S2[c] - 1.f) / (2.f * S1[c]);   // Newton
            done = done && (fabsf(S2[c] - 1.f) < 4e-6f);
        }
        if (done) break;                    // wave-uniform
    }

#pragma unroll
    for (int c = 0; c < 4; ++c) {
        float4 pv;
        float v0 = fmaxf(z[c].x - tau[c], 0.f);
        float v1 = fmaxf(z[c].y - tau[c], 0.f);
        float v2 = fmaxf(z[c].z - tau[c], 0.f);
        float v3 = fmaxf(z[c].w - tau[c], 0.f);
        pv.x = v0 * v0; pv.y = v1 * v1; pv.z = v2 * v2; pv.w = v3 * v3;
        *(float4*)&s_z[w * 4 + c][4 * lane] = pv;
    }
    __syncthreads();
    // transposed store: cwT[n][f], 16 consecutive floats per thread
    const int nl = tid >> 4;
    const int f0 = (tid & 15) * 16;
#pragma unroll
    for (int j = 0; j < 4; ++j) {
        float4 v = *(const float4*)&s_z[nl][f0 + 4 * j];
        *(float4*)&cwT[(n0 + nl) * F_IN + f0 + 4 * j] = v;
    }
}

// ---------------------------------------------------------------------------
// Kernel 2 (fused): per block = 8 trees x 64 batch rows.
//   Phase 1: fv tile [48 n x 64 b] = cwT[48 cols] x input[64 rows] (fp32,
//            K staged in 4 chunks of 64) -> sFV in LDS (never hits HBM).
//   Phase 2: soft binning + DP leaf product + response dot, coalesced output.
// ---------------------------------------------------------------------------
__global__ __launch_bounds__(256) void k_fused(const float* __restrict__ cwT,
                                               const float* __restrict__ inp,
                                               const float* __restrict__ thr,
                                               const float* __restrict__ ltemp,
                                               const float* __restrict__ resp,
                                               float* __restrict__ out) {
    const int tb  = blockIdx.x;            // tree block: trees t0g..t0g+7
    const int b0  = blockIdx.y * 64;
    const int t0g = tb * 8;
    const int n0g = tb * 48;               // global fv-column base
    const int tid = threadIdx.x;

    __shared__ float sA[64][48];           // cw chunk   [k][n]
    __shared__ float sB[64][68];           // input chunk[k][b] (stride 68: float4-aligned)
    __shared__ float sFV[48][68];          // fv tile    [n][b]
    __shared__ float sR[8 * 192];          // response, 8 trees
    __shared__ float sO[64][25];           // output staging (+1 pad)

    for (int i = tid; i < 8 * 192; i += 256) sR[i] = resp[t0g * 192 + i];

    const int tx = tid & 15;               // b quad: b = tx*4..+3
    const int ty = tid >> 4;               // n triple: n = ty*3..+2
    const int a_w = tid >> 6;              // sA load: n = i*4 + a_w
    const int a_k = tid & 63;              // sA load: k within chunk
    const int b_b = tid >> 2;              // sB load: batch row
    const int b_k = (tid & 3) * 16;        // sB load: k base
    float acc[3][4] = {};

    for (int k0 = 0; k0 < F_IN; k0 += 64) {
        float a_reg[12];
#pragma unroll
        for (int i = 0; i < 12; ++i)
            a_reg[i] = cwT[(n0g + i * 4 + a_w) * F_IN + k0 + a_k];
        float4 b_reg[4];
#pragma unroll
        for (int i = 0; i < 4; ++i)
            b_reg[i] = *(const float4*)&inp[(b0 + b_b) * F_IN + k0 + b_k + i * 4];
        __syncthreads();
#pragma unroll
        for (int i = 0; i < 12; ++i) sA[a_k][i * 4 + a_w] = a_reg[i];
#pragma unroll
        for (int i = 0; i < 4; ++i) {
            sB[b_k + i * 4 + 0][b_b] = b_reg[i].x;
            sB[b_k + i * 4 + 1][b_b] = b_reg[i].y;
            sB[b_k + i * 4 + 2][b_b] = b_reg[i].z;
            sB[b_k + i * 4 + 3][b_b] = b_reg[i].w;
        }
        __syncthreads();
#pragma unroll 16
        for (int kk = 0; kk < 64; ++kk) {
            float a0 = sA[kk][ty * 3 + 0];
            float a1 = sA[kk][ty * 3 + 1];
            float a2 = sA[kk][ty * 3 + 2];
            float4 bv = *(const float4*)&sB[kk][tx * 4];
            acc[0][0] = fmaf(a0, bv.x, acc[0][0]);
            acc[0][1] = fmaf(a0, bv.y, acc[0][1]);
            acc[0][2] = fmaf(a0, bv.z, acc[0][2]);
            acc[0][3] = fmaf(a0, bv.w, acc[0][3]);
            acc[1][0] = fmaf(a1, bv.x, acc[1][0]);
            acc[1][1] = fmaf(a1, bv.y, acc[1][1]);
            acc[1][2] = fmaf(a1, bv.z, acc[1][2]);
            acc[1][3] = fmaf(a1, bv.w, acc[1][3]);
            acc[2][0] = fmaf(a2, bv.x, acc[2][0]);
            acc[2][1] = fmaf(a2, bv.y, acc[2][1]);
            acc[2][2] = fmaf(a2, bv.z, acc[2][2]);
            acc[2][3] = fmaf(a2, bv.w, acc[2][3]);
        }
    }
#pragma unroll
    for (int r = 0; r < 3; ++r) {
        float4 v = make_float4(acc[r][0], acc[r][1], acc[r][2], acc[r][3]);
        *(float4*)&sFV[ty * 3 + r][tx * 4] = v;
    }
    __syncthreads();

    // Phase 2: 512 (tree,b) pairs, 2 per thread
#pragma unroll
    for (int p = 0; p < 2; ++p) {
        const int pi = p * 256 + tid;
        const int tl = pi >> 6;            // local tree 0..7
        const int b  = pi & 63;
        const int base = (t0g + tl) * 6;
        float bpos[6], bneg[6];
#pragma unroll
        for (int d = 0; d < 6; ++d) {
            float fvv = sFV[tl * 6 + d][b];
            float tlv = (fvv - thr[base + d]) * expf(-ltemp[base + d]);
            float hp = 0.5f * tlv + 0.5f;
            float hn = 0.5f - 0.5f * tlv;
            bpos[d] = fminf(fmaxf(hp, -0.5f), 1.5f);   // bit d == 0
            bneg[d] = fminf(fmaxf(hn, -0.5f), 1.5f);   // bit d == 1
        }
        float pr[64];
        pr[0] = 1.f;
#pragma unroll
        for (int d = 0; d < 6; ++d) {
            int half = 1 << d;
#pragma unroll 32
            for (int i = half - 1; i >= 0; --i) {
                float v = pr[i];
                pr[i + half] = v * bneg[d];
                pr[i]        = v * bpos[d];
            }
        }
        float a0 = 0.f, a1 = 0.f, a2 = 0.f;
        const float* r = &sR[tl * 192];
#pragma unroll
        for (int c = 0; c < 64; ++c) {
            a0 = fmaf(pr[c], r[c], a0);
            a1 = fmaf(pr[c], r[64 + c], a1);
            a2 = fmaf(pr[c], r[128 + c], a2);
        }
        sO[b][tl * 3 + 0] = a0;
        sO[b][tl * 3 + 1] = a1;
        sO[b][tl * 3 + 2] = a2;
    }
    __syncthreads();
    for (int i = tid; i < 64 * 24; i += 256) {
        int row = i / 24, col = i % 24;
        out[(b0 + row) * OUTW + t0g * 3 + col] = sO[row][col];
    }
}

extern "C" void kernel_launch(void* const* d_in, const int* in_sizes, int n_in,
                              void* d_out, int out_size, void* d_ws, size_t ws_size,
                              hipStream_t stream) {
    const float* input = (const float*)d_in[0];   // [512, 256]
    const float* att   = (const float*)d_in[1];   // [256, 3072]
    const float* thr   = (const float*)d_in[2];   // [512, 6]
    const float* ltemp = (const float*)d_in[3];   // [512, 6]
    const float* resp  = (const float*)d_in[4];   // [512, 3, 64]
    float* out = (float*)d_out;                   // [512, 1536]

    float* cwT = (float*)d_ws;                    // [3072, 256]  3 MB (transposed)

    hipLaunchKernelGGL(k_entmax, dim3(NCOLS / 16), dim3(256), 0, stream, att, cwT);
    hipLaunchKernelGGL(k_fused, dim3(NTREES / 8, BATCH / 64), dim3(256), 0, stream,
                       cwT, input, thr, ltemp, resp, out);
}

// Round 5
// 95.693 us; speedup vs baseline: 1.0585x; 1.0585x over previous
//
#include <hip/hip_runtime.h>
#include <math.h>

#define F_IN 256
#define NTREES 512
#define DEPTH 6
#define NCOLS (NTREES * DEPTH)   /* 3072 */
#define BATCH 512
#define OUTW (NTREES * 3)        /* 1536 */

typedef __attribute__((ext_vector_type(8))) short bf16x8;
typedef __attribute__((ext_vector_type(4))) float f32x4;
typedef __attribute__((ext_vector_type(4))) unsigned short u16x4;
typedef __attribute__((ext_vector_type(8))) unsigned short u16x8;

__device__ __forceinline__ unsigned short f2bf(float x) {
    unsigned u = __float_as_uint(x);
    return (unsigned short)((u + 0x7FFFu + ((u >> 16) & 1u)) >> 16);   // RN-even
}
__device__ __forceinline__ void split2(float x, unsigned short& h, unsigned short& l) {
    h = f2bf(x);
    l = f2bf(x - __uint_as_float((unsigned)h << 16));
}

// ---------------------------------------------------------------------------
// Kernel 1: exact 1.5-entmax (Newton root-solve, one wave per column).
// Blocks 0..191: entmax for 16 columns each, output as bf16 hi/lo planes
// cwT_hi/cwT_lo [3072][256] (row-major in F -> MFMA A-frag reads are 16B
// contiguous). Blocks 192..199: convert input [512][256] to in_hi/in_lo.
// ---------------------------------------------------------------------------
__global__ __launch_bounds__(256) void k_entmax(const float* __restrict__ att,
                                                const float* __restrict__ inp,
                                                unsigned short* __restrict__ cwT_hi,
                                                unsigned short* __restrict__ cwT_lo,
                                                unsigned short* __restrict__ in_hi,
                                                unsigned short* __restrict__ in_lo) {
    const int tid = threadIdx.x;

    if (blockIdx.x >= NCOLS / 16) {          // input-conversion blocks
        const int cb = blockIdx.x - NCOLS / 16;       // 0..7
        const float4* src = (const float4*)inp;       // 32768 float4 total
#pragma unroll
        for (int it = 0; it < 16; ++it) {
            int idx = cb * 4096 + it * 256 + tid;     // float4 index
            float4 v = src[idx];
            u16x4 h, l;
            unsigned short th, tl;
            split2(v.x, th, tl); h.x = th; l.x = tl;
            split2(v.y, th, tl); h.y = th; l.y = tl;
            split2(v.z, th, tl); h.z = th; l.z = tl;
            split2(v.w, th, tl); h.w = th; l.w = tl;
            *(u16x4*)&in_hi[idx * 4] = h;
            *(u16x4*)&in_lo[idx * 4] = l;
        }
        return;
    }

    const int n0 = blockIdx.x * 16;
    const int lane = tid & 63;
    const int w = tid >> 6;                 // wave id 0..3
    __shared__ float s_z[16][260];

    const int cld = tid & 15;
#pragma unroll
    for (int it = 0; it < 16; ++it) {
        int f = (tid >> 4) + it * 16;
        s_z[cld][f] = att[f * NCOLS + n0 + cld];
    }
    __syncthreads();

    float4 z[4];
    float m[4], tau[4];
#pragma unroll
    for (int c = 0; c < 4; ++c) {
        float4 v = *(const float4*)&s_z[w * 4 + c][4 * lane];
        z[c] = make_float4(v.x * 0.5f, v.y * 0.5f, v.z * 0.5f, v.w * 0.5f);
        m[c] = fmaxf(fmaxf(z[c].x, z[c].y), fmaxf(z[c].z, z[c].w));
    }
#pragma unroll
    for (int off = 32; off >= 1; off >>= 1)
#pragma unroll
        for (int c = 0; c < 4; ++c)
            m[c] = fmaxf(m[c], __shfl_xor(m[c], off));
#pragma unroll
    for (int c = 0; c < 4; ++c) {
        z[c].x -= m[c]; z[c].y -= m[c]; z[c].z -= m[c]; z[c].w -= m[c];
        tau[c] = -1.0f;                     // f(zmax-1) >= 0 guaranteed
    }

    for (int iter = 0; iter < 14; ++iter) {
        float S1[4], S2[4];
#pragma unroll
        for (int c = 0; c < 4; ++c) {
            float d0 = fmaxf(z[c].x - tau[c], 0.f);
            float d1 = fmaxf(z[c].y - tau[c], 0.f);
            float d2 = fmaxf(z[c].z - tau[c], 0.f);
            float d3 = fmaxf(z[c].w - tau[c], 0.f);
            S1[c] = (d0 + d1) + (d2 + d3);
            S2[c] = fmaf(d0, d0, fmaf(d1, d1, fmaf(d2, d2, d3 * d3)));
        }
#pragma unroll
        for (int off = 32; off >= 1; off >>= 1)
#pragma unroll
            for (int c = 0; c < 4; ++c) {
                S1[c] += __shfl_xor(S1[c], off);
                S2[c] += __shfl_xor(S2[c], off);
            }
        bool done = true;
#pragma unroll
        for (int c = 0; c < 4; ++c) {
            tau[c] += (S2[c] - 1.f) / (2.f * S1[c]);   // Newton
            done = done && (fabsf(S2[c] - 1.f) < 4e-6f);
        }
        if (done) break;                    // wave-uniform
    }

#pragma unroll
    for (int c = 0; c < 4; ++c) {
        float4 pv;
        float v0 = fmaxf(z[c].x - tau[c], 0.f);
        float v1 = fmaxf(z[c].y - tau[c], 0.f);
        float v2 = fmaxf(z[c].z - tau[c], 0.f);
        float v3 = fmaxf(z[c].w - tau[c], 0.f);
        pv.x = v0 * v0; pv.y = v1 * v1; pv.z = v2 * v2; pv.w = v3 * v3;
        *(float4*)&s_z[w * 4 + c][4 * lane] = pv;
    }
    __syncthreads();
    // transposed hi/lo store: cwT_*[n][f], 16 consecutive elems per thread
    const int nl = tid >> 4;
    const int f0 = (tid & 15) * 16;
#pragma unroll
    for (int j = 0; j < 2; ++j) {
        u16x8 hv, lv;
#pragma unroll
        for (int e = 0; e < 8; ++e) {
            unsigned short h, l;
            split2(s_z[nl][f0 + j * 8 + e], h, l);
            hv[e] = h; lv[e] = l;
        }
        *(u16x8*)&cwT_hi[(n0 + nl) * F_IN + f0 + j * 8] = hv;
        *(u16x8*)&cwT_lo[(n0 + nl) * F_IN + f0 + j * 8] = lv;
    }
}

// ---------------------------------------------------------------------------
// Kernel 2: fv[n][b] = sum_f cwT[n][f] * inp[b][f] via split-bf16 MFMA
// (hi*hi + hi*lo + lo*hi; dropped lo*lo ~ 2^-18 rel). A-Bt form: both
// operands row-major in K -> identical 16B-contiguous fragment loads
// straight from global (L2-resident working set, no LDS, no barriers).
// Block = 128 thr (2 waves); wave tile 32n x 64b = 2 m-tiles x 4 b-tiles.
// ---------------------------------------------------------------------------
__global__ __launch_bounds__(128) void k_gemm(const unsigned short* __restrict__ Ah,
                                              const unsigned short* __restrict__ Al,
                                              const unsigned short* __restrict__ Bh,
                                              const unsigned short* __restrict__ Bl,
                                              float* __restrict__ fv) {
    const int tid = threadIdx.x;
    const int wave = tid >> 6, lane = tid & 63;
    const int quad = lane >> 4, lr = lane & 15;
    const int n0 = blockIdx.x * 32;
    const int bw = blockIdx.y * 128 + wave * 64;

    const unsigned short* pah = Ah + (n0 + lr) * F_IN + quad * 8;
    const unsigned short* pal = Al + (n0 + lr) * F_IN + quad * 8;
    const unsigned short* pbh = Bh + (bw + lr) * F_IN + quad * 8;
    const unsigned short* pbl = Bl + (bw + lr) * F_IN + quad * 8;

    f32x4 acc[2][4];
#pragma unroll
    for (int i = 0; i < 2; ++i)
#pragma unroll
        for (int j = 0; j < 4; ++j)
            acc[i][j] = (f32x4){0.f, 0.f, 0.f, 0.f};

#pragma unroll
    for (int k0 = 0; k0 < F_IN; k0 += 32) {
        bf16x8 ah[2], al[2], bh[4], bl[4];
#pragma unroll
        for (int i = 0; i < 2; ++i) {
            ah[i] = *(const bf16x8*)(pah + i * 16 * F_IN + k0);
            al[i] = *(const bf16x8*)(pal + i * 16 * F_IN + k0);
        }
#pragma unroll
        for (int j = 0; j < 4; ++j) {
            bh[j] = *(const bf16x8*)(pbh + j * 16 * F_IN + k0);
            bl[j] = *(const bf16x8*)(pbl + j * 16 * F_IN + k0);
        }
#pragma unroll
        for (int i = 0; i < 2; ++i)
#pragma unroll
            for (int j = 0; j < 4; ++j) {
                acc[i][j] = __builtin_amdgcn_mfma_f32_16x16x32_bf16(ah[i], bh[j], acc[i][j], 0, 0, 0);
                acc[i][j] = __builtin_amdgcn_mfma_f32_16x16x32_bf16(ah[i], bl[j], acc[i][j], 0, 0, 0);
                acc[i][j] = __builtin_amdgcn_mfma_f32_16x16x32_bf16(al[i], bh[j], acc[i][j], 0, 0, 0);
            }
    }

    // C/D layout: col = lane&15 (b), row = quad*4 + r (n)  [m89-verified]
#pragma unroll
    for (int i = 0; i < 2; ++i)
#pragma unroll
        for (int j = 0; j < 4; ++j)
#pragma unroll
            for (int r = 0; r < 4; ++r)
                fv[(n0 + 16 * i + quad * 4 + r) * BATCH + bw + 16 * j + lr] = acc[i][j][r];
}

// ---------------------------------------------------------------------------
// Kernel 3: soft binning + DP leaf-product + response contraction.
// ---------------------------------------------------------------------------
__global__ __launch_bounds__(256) void k_tree(const float* __restrict__ fv,
                                              const float* __restrict__ thr,
                                              const float* __restrict__ ltemp,
                                              const float* __restrict__ resp,
                                              float* __restrict__ out) {
    const int t0 = blockIdx.x * 8;
    const int b0 = blockIdx.y * 64;
    const int tid = threadIdx.x;
    const int bl = tid & 63;
    const int b = b0 + bl;
    const int tsub = tid >> 6;                 // 0..3
    __shared__ float s_resp[8 * 192];
    __shared__ float s_out[64][25];

    for (int i = tid; i < 8 * 192; i += 256)
        s_resp[i] = resp[t0 * 192 + i];
    __syncthreads();

#pragma unroll
    for (int half_t = 0; half_t < 2; ++half_t) {
        const int ttl = tsub + half_t * 4;
        const int tt = t0 + ttl;
        float bpos[6], bneg[6];
#pragma unroll
        for (int d = 0; d < 6; ++d) {
            float fvv = fv[(tt * 6 + d) * BATCH + b];
            float tl = (fvv - thr[tt * 6 + d]) * expf(-ltemp[tt * 6 + d]);
            float hp = 0.5f * tl + 0.5f;
            float hn = 0.5f - 0.5f * tl;
            bpos[d] = fminf(fmaxf(hp, -0.5f), 1.5f);
            bneg[d] = fminf(fmaxf(hn, -0.5f), 1.5f);
        }
        float p[64];
        p[0] = 1.f;
#pragma unroll
        for (int d = 0; d < 6; ++d) {
            int half = 1 << d;
#pragma unroll 32
            for (int i = half - 1; i >= 0; --i) {
                float v = p[i];
                p[i + half] = v * bneg[d];
                p[i]        = v * bpos[d];
            }
        }
        float a0 = 0.f, a1 = 0.f, a2 = 0.f;
        const float* r = &s_resp[ttl * 192];
#pragma unroll
        for (int c = 0; c < 64; ++c) {
            a0 = fmaf(p[c], r[c], a0);
            a1 = fmaf(p[c], r[64 + c], a1);
            a2 = fmaf(p[c], r[128 + c], a2);
        }
        s_out[bl][ttl * 3 + 0] = a0;
        s_out[bl][ttl * 3 + 1] = a1;
        s_out[bl][ttl * 3 + 2] = a2;
    }
    __syncthreads();
    for (int i = tid; i < 64 * 24; i += 256) {
        int row = i / 24, col = i % 24;
        out[(b0 + row) * OUTW + t0 * 3 + col] = s_out[row][col];
    }
}

extern "C" void kernel_launch(void* const* d_in, const int* in_sizes, int n_in,
                              void* d_out, int out_size, void* d_ws, size_t ws_size,
                              hipStream_t stream) {
    const float* input = (const float*)d_in[0];   // [512, 256]
    const float* att   = (const float*)d_in[1];   // [256, 3072]
    const float* thr   = (const float*)d_in[2];   // [512, 6]
    const float* ltemp = (const float*)d_in[3];   // [512, 6]
    const float* resp  = (const float*)d_in[4];   // [512, 3, 64]
    float* out = (float*)d_out;                   // [512, 1536]

    unsigned short* cwT_hi = (unsigned short*)d_ws;          // [3072][256] bf16
    unsigned short* cwT_lo = cwT_hi + NCOLS * F_IN;
    unsigned short* in_hi  = cwT_lo + NCOLS * F_IN;          // [512][256] bf16
    unsigned short* in_lo  = in_hi + BATCH * F_IN;
    float* fv = (float*)(in_lo + BATCH * F_IN);              // [3072][512] fp32

    hipLaunchKernelGGL(k_entmax, dim3(NCOLS / 16 + 8), dim3(256), 0, stream,
                       att, input, cwT_hi, cwT_lo, in_hi, in_lo);
    hipLaunchKernelGGL(k_gemm, dim3(NCOLS / 32, BATCH / 128), dim3(128), 0, stream,
                       cwT_hi, cwT_lo, in_hi, in_lo, fv);
    hipLaunchKernelGGL(k_tree, dim3(NTREES / 8, BATCH / 64), dim3(256), 0, stream,
                       fv, thr, ltemp, resp, out);
}

// Round 6
// 91.387 us; speedup vs baseline: 1.1084x; 1.0471x over previous
//
#include <hip/hip_runtime.h>
#include <math.h>

#define F_IN 256
#define NTREES 512
#define DEPTH 6
#define NCOLS (NTREES * DEPTH)   /* 3072 */
#define BATCH 512
#define OUTW (NTREES * 3)        /* 1536 */

typedef __attribute__((ext_vector_type(8))) short bf16x8;
typedef __attribute__((ext_vector_type(4))) float f32x4;
typedef __attribute__((ext_vector_type(4))) unsigned short u16x4;
typedef __attribute__((ext_vector_type(8))) unsigned short u16x8;

__device__ __forceinline__ unsigned short f2bf(float x) {
    unsigned u = __float_as_uint(x);
    return (unsigned short)((u + 0x7FFFu + ((u >> 16) & 1u)) >> 16);   // RN-even
}
__device__ __forceinline__ void split2(float x, unsigned short& h, unsigned short& l) {
    h = f2bf(x);
    l = f2bf(x - __uint_as_float((unsigned)h << 16));
}

// ---------------------------------------------------------------------------
// Kernel 1: exact 1.5-entmax (Newton root-solve, one wave per column).
// Blocks 0..191: entmax, output as bf16 hi/lo planes cwT_hi/cwT_lo [3072][256].
// Blocks 192..199: convert input [512][256] to in_hi/in_lo.
// ---------------------------------------------------------------------------
__global__ __launch_bounds__(256) void k_entmax(const float* __restrict__ att,
                                                const float* __restrict__ inp,
                                                unsigned short* __restrict__ cwT_hi,
                                                unsigned short* __restrict__ cwT_lo,
                                                unsigned short* __restrict__ in_hi,
                                                unsigned short* __restrict__ in_lo) {
    const int tid = threadIdx.x;

    if (blockIdx.x >= NCOLS / 16) {          // input-conversion blocks
        const int cb = blockIdx.x - NCOLS / 16;       // 0..7
        const float4* src = (const float4*)inp;
#pragma unroll
        for (int it = 0; it < 16; ++it) {
            int idx = cb * 4096 + it * 256 + tid;     // float4 index
            float4 v = src[idx];
            u16x4 h, l;
            unsigned short th, tl;
            split2(v.x, th, tl); h.x = th; l.x = tl;
            split2(v.y, th, tl); h.y = th; l.y = tl;
            split2(v.z, th, tl); h.z = th; l.z = tl;
            split2(v.w, th, tl); h.w = th; l.w = tl;
            *(u16x4*)&in_hi[idx * 4] = h;
            *(u16x4*)&in_lo[idx * 4] = l;
        }
        return;
    }

    const int n0 = blockIdx.x * 16;
    const int lane = tid & 63;
    const int w = tid >> 6;                 // wave id 0..3
    __shared__ float s_z[16][260];

    const int cld = tid & 15;
#pragma unroll
    for (int it = 0; it < 16; ++it) {
        int f = (tid >> 4) + it * 16;
        s_z[cld][f] = att[f * NCOLS + n0 + cld];
    }
    __syncthreads();

    float4 z[4];
    float m[4], tau[4];
#pragma unroll
    for (int c = 0; c < 4; ++c) {
        float4 v = *(const float4*)&s_z[w * 4 + c][4 * lane];
        z[c] = make_float4(v.x * 0.5f, v.y * 0.5f, v.z * 0.5f, v.w * 0.5f);
        m[c] = fmaxf(fmaxf(z[c].x, z[c].y), fmaxf(z[c].z, z[c].w));
    }
#pragma unroll
    for (int off = 32; off >= 1; off >>= 1)
#pragma unroll
        for (int c = 0; c < 4; ++c)
            m[c] = fmaxf(m[c], __shfl_xor(m[c], off));
#pragma unroll
    for (int c = 0; c < 4; ++c) {
        z[c].x -= m[c]; z[c].y -= m[c]; z[c].z -= m[c]; z[c].w -= m[c];
        tau[c] = -1.0f;                     // f(zmax-1) >= 0 guaranteed
    }

    for (int iter = 0; iter < 14; ++iter) {
        float S1[4], S2[4];
#pragma unroll
        for (int c = 0; c < 4; ++c) {
            float d0 = fmaxf(z[c].x - tau[c], 0.f);
            float d1 = fmaxf(z[c].y - tau[c], 0.f);
            float d2 = fmaxf(z[c].z - tau[c], 0.f);
            float d3 = fmaxf(z[c].w - tau[c], 0.f);
            S1[c] = (d0 + d1) + (d2 + d3);
            S2[c] = fmaf(d0, d0, fmaf(d1, d1, fmaf(d2, d2, d3 * d3)));
        }
#pragma unroll
        for (int off = 32; off >= 1; off >>= 1)
#pragma unroll
            for (int c = 0; c < 4; ++c) {
                S1[c] += __shfl_xor(S1[c], off);
                S2[c] += __shfl_xor(S2[c], off);
            }
        bool done = true;
#pragma unroll
        for (int c = 0; c < 4; ++c) {
            tau[c] += (S2[c] - 1.f) / (2.f * S1[c]);   // Newton
            done = done && (fabsf(S2[c] - 1.f) < 4e-6f);
        }
        if (done) break;                    // wave-uniform
    }

#pragma unroll
    for (int c = 0; c < 4; ++c) {
        float4 pv;
        float v0 = fmaxf(z[c].x - tau[c], 0.f);
        float v1 = fmaxf(z[c].y - tau[c], 0.f);
        float v2 = fmaxf(z[c].z - tau[c], 0.f);
        float v3 = fmaxf(z[c].w - tau[c], 0.f);
        pv.x = v0 * v0; pv.y = v1 * v1; pv.z = v2 * v2; pv.w = v3 * v3;
        *(float4*)&s_z[w * 4 + c][4 * lane] = pv;
    }
    __syncthreads();
    const int nl = tid >> 4;
    const int f0 = (tid & 15) * 16;
#pragma unroll
    for (int j = 0; j < 2; ++j) {
        u16x8 hv, lv;
#pragma unroll
        for (int e = 0; e < 8; ++e) {
            unsigned short h, l;
            split2(s_z[nl][f0 + j * 8 + e], h, l);
            hv[e] = h; lv[e] = l;
        }
        *(u16x8*)&cwT_hi[(n0 + nl) * F_IN + f0 + j * 8] = hv;
        *(u16x8*)&cwT_lo[(n0 + nl) * F_IN + f0 + j * 8] = lv;
    }
}

// ---------------------------------------------------------------------------
// Kernel 2 (fused GEMM + tree): block = 8 trees (48 n-cols) x 128 batch,
// 4 waves. Phase 1: each wave computes 48n x 32b via split-bf16 MFMA
// (hi*hi + hi*lo + lo*hi) straight from L2-resident hi/lo planes -> sFV in
// LDS (fv never hits global). Phase 2: soft binning (exp(-ltemp) precomputed
// per block) + DP leaf product + response dot, coalesced output via LDS.
// Grid = 64 x 4 = 256 blocks = 1/CU.
// ---------------------------------------------------------------------------
__global__ __launch_bounds__(256) void k_fused(const unsigned short* __restrict__ Ah,
                                               const unsigned short* __restrict__ Al,
                                               const unsigned short* __restrict__ Bh,
                                               const unsigned short* __restrict__ Bl,
                                               const float* __restrict__ thr,
                                               const float* __restrict__ ltemp,
                                               const float* __restrict__ resp,
                                               float* __restrict__ out) {
    const int tb  = blockIdx.x;            // tree block
    const int b0  = blockIdx.y * 128;
    const int t0g = tb * 8;
    const int n0g = tb * 48;               // fv-column base = t0g*6
    const int tid = threadIdx.x;
    const int wave = tid >> 6, lane = tid & 63;
    const int quad = lane >> 4, lr = lane & 15;

    __shared__ float sFV[48][132];         // fv tile [n][b], pad 132
    __shared__ float sR[8 * 192];          // response, 8 trees
    __shared__ float sTH[48], sET[48];     // thresholds, exp(-ltemp)
    __shared__ float sO[128][25];          // output staging

    for (int i = tid; i < 8 * 192; i += 256) sR[i] = resp[t0g * 192 + i];
    if (tid < 48) {
        sTH[tid] = thr[n0g + tid];
        sET[tid] = expf(-ltemp[n0g + tid]);
    }

    // ---- Phase 1: MFMA GEMM, wave tile = 48n x 32b ----
    const int bw = b0 + wave * 32;
    const unsigned short* pah = Ah + (n0g + lr) * F_IN + quad * 8;
    const unsigned short* pal = Al + (n0g + lr) * F_IN + quad * 8;
    const unsigned short* pbh = Bh + (bw + lr) * F_IN + quad * 8;
    const unsigned short* pbl = Bl + (bw + lr) * F_IN + quad * 8;

    f32x4 acc[3][2];
#pragma unroll
    for (int i = 0; i < 3; ++i)
#pragma unroll
        for (int j = 0; j < 2; ++j)
            acc[i][j] = (f32x4){0.f, 0.f, 0.f, 0.f};

#pragma unroll
    for (int k0 = 0; k0 < F_IN; k0 += 32) {
        bf16x8 ah[3], al[3], bh[2], bl[2];
#pragma unroll
        for (int i = 0; i < 3; ++i) {
            ah[i] = *(const bf16x8*)(pah + i * 16 * F_IN + k0);
            al[i] = *(const bf16x8*)(pal + i * 16 * F_IN + k0);
        }
#pragma unroll
        for (int j = 0; j < 2; ++j) {
            bh[j] = *(const bf16x8*)(pbh + j * 16 * F_IN + k0);
            bl[j] = *(const bf16x8*)(pbl + j * 16 * F_IN + k0);
        }
#pragma unroll
        for (int i = 0; i < 3; ++i)
#pragma unroll
            for (int j = 0; j < 2; ++j) {
                acc[i][j] = __builtin_amdgcn_mfma_f32_16x16x32_bf16(ah[i], bh[j], acc[i][j], 0, 0, 0);
                acc[i][j] = __builtin_amdgcn_mfma_f32_16x16x32_bf16(ah[i], bl[j], acc[i][j], 0, 0, 0);
                acc[i][j] = __builtin_amdgcn_mfma_f32_16x16x32_bf16(al[i], bh[j], acc[i][j], 0, 0, 0);
            }
    }
    // C/D layout: col = lane&15 (b), row = quad*4 + r (n)  [m89-verified]
#pragma unroll
    for (int i = 0; i < 3; ++i)
#pragma unroll
        for (int j = 0; j < 2; ++j)
#pragma unroll
            for (int r = 0; r < 4; ++r)
                sFV[16 * i + quad * 4 + r][wave * 32 + 16 * j + lr] = acc[i][j][r];
    __syncthreads();

    // ---- Phase 2: 8 trees x 128 b = 1024 pairs, 4 per thread ----
#pragma unroll
    for (int p = 0; p < 4; ++p) {
        const int pi = p * 256 + tid;
        const int tl = pi >> 7;            // local tree 0..7
        const int b  = pi & 127;
        float bpos[6], bneg[6];
#pragma unroll
        for (int d = 0; d < 6; ++d) {
            float fvv = sFV[tl * 6 + d][b];
            float tlv = (fvv - sTH[tl * 6 + d]) * sET[tl * 6 + d];
            float hp = 0.5f * tlv + 0.5f;
            float hn = 0.5f - 0.5f * tlv;
            bpos[d] = fminf(fmaxf(hp, -0.5f), 1.5f);   // bit d == 0
            bneg[d] = fminf(fmaxf(hn, -0.5f), 1.5f);   // bit d == 1
        }
        float pr[64];
        pr[0] = 1.f;
#pragma unroll
        for (int d = 0; d < 6; ++d) {
            int half = 1 << d;
#pragma unroll 32
            for (int i = half - 1; i >= 0; --i) {
                float v = pr[i];
                pr[i + half] = v * bneg[d];
                pr[i]        = v * bpos[d];
            }
        }
        float a0 = 0.f, a1 = 0.f, a2 = 0.f;
        const float* r = &sR[tl * 192];
#pragma unroll
        for (int c = 0; c < 64; ++c) {
            a0 = fmaf(pr[c], r[c], a0);
            a1 = fmaf(pr[c], r[64 + c], a1);
            a2 = fmaf(pr[c], r[128 + c], a2);
        }
        sO[b][tl * 3 + 0] = a0;
        sO[b][tl * 3 + 1] = a1;
        sO[b][tl * 3 + 2] = a2;
    }
    __syncthreads();
    for (int i = tid; i < 128 * 24; i += 256) {
        int row = i / 24, col = i % 24;
        out[(b0 + row) * OUTW + t0g * 3 + col] = sO[row][col];
    }
}

extern "C" void kernel_launch(void* const* d_in, const int* in_sizes, int n_in,
                              void* d_out, int out_size, void* d_ws, size_t ws_size,
                              hipStream_t stream) {
    const float* input = (const float*)d_in[0];   // [512, 256]
    const float* att   = (const float*)d_in[1];   // [256, 3072]
    const float* thr   = (const float*)d_in[2];   // [512, 6]
    const float* ltemp = (const float*)d_in[3];   // [512, 6]
    const float* resp  = (const float*)d_in[4];   // [512, 3, 64]
    float* out = (float*)d_out;                   // [512, 1536]

    unsigned short* cwT_hi = (unsigned short*)d_ws;          // [3072][256] bf16
    unsigned short* cwT_lo = cwT_hi + NCOLS * F_IN;
    unsigned short* in_hi  = cwT_lo + NCOLS * F_IN;          // [512][256] bf16
    unsigned short* in_lo  = in_hi + BATCH * F_IN;

    hipLaunchKernelGGL(k_entmax, dim3(NCOLS / 16 + 8), dim3(256), 0, stream,
                       att, input, cwT_hi, cwT_lo, in_hi, in_lo);
    hipLaunchKernelGGL(k_fused, dim3(NTREES / 8, BATCH / 128), dim3(256), 0, stream,
                       cwT_hi, cwT_lo, in_hi, in_lo, thr, ltemp, resp, out);
}